// Round 1
// baseline (901.584 us; speedup 1.0000x reference)
//
#include <hip/hip_runtime.h>
#include <hip/hip_bf16.h>
#include <cstdint>
#include <math.h>

// ---------------------------------------------------------------------------
// MultiHeadAttention: B=512, T=128, D=768, H=12, hd=64. fp32 in/out,
// bf16 MFMA compute (harness threshold is 8*bf16_eps*|out|max).
//
// Stages:
//   1) cast x (fp32) -> bf16                     [M=65536 x 768]
//   2) transpose+cast Wq/Wk/Wv -> Wqkv^T bf16    [2304 x 768], Wo^T [768 x 768]
//   3) GEMM qkv = x * Wqkv   (bf16 out)          [65536 x 2304]
//   4) attention per (b,h): S=QK^T, causal softmax, ctx=P*V
//      ctx written over the Q region of qkv (cols 0..767) -- safe: each block
//      stages its own Q slice into LDS before overwriting it, blocks disjoint.
//   5) GEMM out = ctx * Wo + bo (fp32 out)
// ---------------------------------------------------------------------------

typedef __bf16 bf16;
typedef __bf16 bf16x8 __attribute__((ext_vector_type(8)));
typedef float f32x4 __attribute__((ext_vector_type(4)));

#define MFMA16(a, b, c) __builtin_amdgcn_mfma_f32_16x16x32_bf16((a), (b), (c), 0, 0, 0)

// async global->LDS, 16B per lane; LDS dest = uniform base + lane*16
#define GLD_LDS16(gp, lp)                                                       \
  __builtin_amdgcn_global_load_lds(                                             \
      (const __attribute__((address_space(1))) void*)(gp),                      \
      (__attribute__((address_space(3))) void*)(lp), 16, 0, 0)

// ---------------------------------------------------------------------------
// Stage 1: fp32 -> bf16 cast, 4 elems/thread
// ---------------------------------------------------------------------------
__global__ __launch_bounds__(256) void cast_x_bf16(const float* __restrict__ in,
                                                   bf16* __restrict__ out, int n) {
  int i = (blockIdx.x * 256 + threadIdx.x) * 4;
  if (i < n) {
    float4 v = *(const float4*)(in + i);
    bf16 o[4] = {(bf16)v.x, (bf16)v.y, (bf16)v.z, (bf16)v.w};
    *(uint2*)(out + i) = *(const uint2*)o;
  }
}

// ---------------------------------------------------------------------------
// Stage 2: 768x768 transpose + cast: Out[n][k] = W[k][n]
// ---------------------------------------------------------------------------
__global__ __launch_bounds__(256) void transpose_cast_w(const float* __restrict__ W,
                                                        bf16* __restrict__ Out) {
  __shared__ float t[32][33];
  int bx = blockIdx.x * 32;  // k tile
  int by = blockIdx.y * 32;  // n tile
  int tx = threadIdx.x, ty = threadIdx.y;  // block (32,8)
  for (int i = 0; i < 32; i += 8)
    t[ty + i][tx] = W[(size_t)(bx + ty + i) * 768 + by + tx];
  __syncthreads();
  for (int i = 0; i < 32; i += 8)
    Out[(size_t)(by + ty + i) * 768 + bx + tx] = (bf16)t[tx][ty + i];
}

// ---------------------------------------------------------------------------
// Stage 3/5: bf16 GEMM, C[M,N] = A[M,K] * Bt[N,K]^T, 128x128 tile, BK=32.
// 256 threads = 4 waves in 2x2, each wave 64x64 = 4x4 frags of 16x16x32 MFMA.
// Staging via global_load_lds width 16 (m97 pattern); LDS tiles [128][32]
// unpadded (required: global_load_lds dest is base + lane*16).
// ---------------------------------------------------------------------------
template <bool OUT_F32>
__global__ __launch_bounds__(256) void gemm128(const bf16* __restrict__ A, int lda,
                                               const bf16* __restrict__ Bt, int ldb,
                                               void* __restrict__ Cout, int ldc,
                                               const float* __restrict__ bias, int K) {
  __shared__ bf16 sA[128 * 32];
  __shared__ bf16 sB[128 * 32];
  const int tid = threadIdx.x;
  const int lane = tid & 63;
  const int w = tid >> 6;
  const int wm = (w & 1) * 64;
  const int wn = (w >> 1) * 64;
  const int m0 = blockIdx.x * 128;
  const int n0 = blockIdx.y * 128;

  f32x4 acc[4][4];
  for (int i = 0; i < 4; ++i)
    for (int j = 0; j < 4; ++j) acc[i][j] = (f32x4){0.f, 0.f, 0.f, 0.f};

  // per-lane staging coords: chunk covers 512 elems = 16 rows of 32
  const int lm = lane & 15;
  const int kq = (lane >> 4) * 8;

  for (int k0 = 0; k0 < K; k0 += 32) {
    for (int i = 0; i < 2; ++i) {
      int chunk = w * 2 + i;
      int e = chunk * 512 + lane * 8;
      int r = e >> 5;     // /32: tile row
      int c = e & 31;     // k within tile
      GLD_LDS16(A + (size_t)(m0 + r) * lda + k0 + c, sA + chunk * 512);
      GLD_LDS16(Bt + (size_t)(n0 + r) * ldb + k0 + c, sB + chunk * 512);
    }
    __syncthreads();  // compiler drains vmcnt before s_barrier

    bf16x8 af[4], bfr[4];
    for (int mi = 0; mi < 4; ++mi)
      af[mi] = *(const bf16x8*)(sA + (wm + mi * 16 + lm) * 32 + kq);
    for (int ni = 0; ni < 4; ++ni)
      bfr[ni] = *(const bf16x8*)(sB + (wn + ni * 16 + lm) * 32 + kq);
    for (int mi = 0; mi < 4; ++mi)
      for (int ni = 0; ni < 4; ++ni)
        acc[mi][ni] = MFMA16(af[mi], bfr[ni], acc[mi][ni]);
    __syncthreads();
  }

  // epilogue: C/D layout col=lane&15, row=(lane>>4)*4+reg  [m89/m91]
  const int lr = (lane >> 4) * 4;
  for (int mi = 0; mi < 4; ++mi)
    for (int ni = 0; ni < 4; ++ni) {
      int col = n0 + wn + ni * 16 + lm;
      for (int r = 0; r < 4; ++r) {
        int row = m0 + wm + mi * 16 + lr + r;
        float v = acc[mi][ni][r];
        if (OUT_F32)
          ((float*)Cout)[(size_t)row * ldc + col] = v + bias[col];
        else
          ((bf16*)Cout)[(size_t)row * ldc + col] = (bf16)v;
      }
    }
}

// ---------------------------------------------------------------------------
// Stage 4: attention, one block (256 thr, 4 waves) per (b,h).
// LDS strides padded (72/136) to break 128B-row bank alignment.
// ---------------------------------------------------------------------------
__global__ __launch_bounds__(256) void attn_kernel(const bf16* __restrict__ qkv,
                                                   bf16* __restrict__ ctx) {
  constexpr int LDQ = 2304;
  constexpr int SQS = 72;   // sQ/sK row stride (64 cols + pad)
  constexpr int SPS = 136;  // sP/sVt row stride (128 cols + pad)
  __shared__ bf16 smem[27136];              // 54272 B
  bf16* sQ = smem;                          // [128][72]
  bf16* sK = smem + 128 * SQS;              // [128][72]
  bf16* sVt = smem + 2 * 128 * SQS;         // [64][136]  Vt[d][t] = V[t][d]
  bf16* sP = smem;                          // [128][136] aliases sQ+sK

  const int bh = blockIdx.x;
  const int b = bh / 12, h = bh % 12;
  const bf16* Qg = qkv + (size_t)b * 128 * LDQ + h * 64;
  const bf16* Kg = Qg + 768;
  const bf16* Vg = Qg + 1536;

  const int tid = threadIdx.x;
  // ---- load Q,K row-major; V transposed ----
  {
    int row = tid >> 1, half = tid & 1;
    const uint4* qsrc = (const uint4*)(Qg + (size_t)row * LDQ + half * 32);
    const uint4* ksrc = (const uint4*)(Kg + (size_t)row * LDQ + half * 32);
    const uint4* vsrc = (const uint4*)(Vg + (size_t)row * LDQ + half * 32);
    uint4* qdst = (uint4*)(sQ + row * SQS + half * 32);
    uint4* kdst = (uint4*)(sK + row * SQS + half * 32);
    uint4 vt[4];
    for (int i = 0; i < 4; ++i) {
      qdst[i] = qsrc[i];
      kdst[i] = ksrc[i];
      vt[i] = vsrc[i];
    }
    const bf16* tp = (const bf16*)vt;
    for (int d = 0; d < 32; ++d) sVt[(half * 32 + d) * SPS + row] = tp[d];
  }
  __syncthreads();

  const int lane = tid & 63;
  const int w = tid >> 6;      // wave handles rows w*32 .. w*32+31
  const int lm = lane & 15;
  const int kq = (lane >> 4) * 8;
  const int lr = (lane >> 4) * 4;

  // ---- S = Q K^T : 2 row-subtiles x 8 col-subtiles per wave ----
  f32x4 sacc[2][8];
  for (int i = 0; i < 2; ++i)
    for (int j = 0; j < 8; ++j) sacc[i][j] = (f32x4){0.f, 0.f, 0.f, 0.f};
  for (int kk = 0; kk < 64; kk += 32) {
    bf16x8 aq[2], bk[8];
    for (int mi = 0; mi < 2; ++mi)
      aq[mi] = *(const bf16x8*)(sQ + (w * 32 + mi * 16 + lm) * SQS + kk + kq);
    for (int ni = 0; ni < 8; ++ni)
      bk[ni] = *(const bf16x8*)(sK + (ni * 16 + lm) * SQS + kk + kq);
    for (int mi = 0; mi < 2; ++mi)
      for (int ni = 0; ni < 8; ++ni)
        sacc[mi][ni] = MFMA16(aq[mi], bk[ni], sacc[mi][ni]);
  }

  // ---- causal softmax (scale=1/8). Row lives in (mi, reg); cols across
  // lanes (lane&15) and ni. Reduce over ni in-register, lanes via shfl_xor.
  float inv[2][4];
  for (int mi = 0; mi < 2; ++mi) {
    for (int r = 0; r < 4; ++r) {
      int row = w * 32 + mi * 16 + lr + r;
      float vals[8];
      float mx = -INFINITY;
      for (int ni = 0; ni < 8; ++ni) {
        int col = ni * 16 + lm;
        float v = sacc[mi][ni][r] * 0.125f;
        if (col > row) v = -INFINITY;
        vals[ni] = v;
        mx = fmaxf(mx, v);
      }
      for (int off = 1; off < 16; off <<= 1) mx = fmaxf(mx, __shfl_xor(mx, off, 64));
      float sum = 0.f;
      for (int ni = 0; ni < 8; ++ni) {
        float p = __expf(vals[ni] - mx);  // exp(-inf)=0
        vals[ni] = p;
        sum += p;
      }
      for (int off = 1; off < 16; off <<= 1) sum += __shfl_xor(sum, off, 64);
      inv[mi][r] = 1.f / sum;
      for (int ni = 0; ni < 8; ++ni) sacc[mi][ni][r] = vals[ni];
    }
  }
  __syncthreads();  // all waves done reading sQ/sK before sP overwrites them

  // ---- write unnormalized P (bf16) to LDS; normalize in PV epilogue ----
  for (int mi = 0; mi < 2; ++mi)
    for (int ni = 0; ni < 8; ++ni)
      for (int r = 0; r < 4; ++r) {
        int row = w * 32 + mi * 16 + lr + r;
        int col = ni * 16 + lm;
        sP[row * SPS + col] = (bf16)sacc[mi][ni][r];
      }
  __syncthreads();

  // ---- ctx = P * V : 2 row-subtiles x 4 col-subtiles per wave ----
  f32x4 oacc[2][4];
  for (int i = 0; i < 2; ++i)
    for (int j = 0; j < 4; ++j) oacc[i][j] = (f32x4){0.f, 0.f, 0.f, 0.f};
  for (int kk = 0; kk < 128; kk += 32) {
    bf16x8 ap[2], bv[4];
    for (int mi = 0; mi < 2; ++mi)
      ap[mi] = *(const bf16x8*)(sP + (w * 32 + mi * 16 + lm) * SPS + kk + kq);
    for (int ci = 0; ci < 4; ++ci)
      bv[ci] = *(const bf16x8*)(sVt + (ci * 16 + lm) * SPS + kk + kq);
    for (int mi = 0; mi < 2; ++mi)
      for (int ci = 0; ci < 4; ++ci)
        oacc[mi][ci] = MFMA16(ap[mi], bv[ci], oacc[mi][ci]);
  }

  // ---- write ctx over the Q region ----
  bf16* Cg = ctx + (size_t)b * 128 * LDQ + h * 64;
  for (int mi = 0; mi < 2; ++mi)
    for (int ci = 0; ci < 4; ++ci)
      for (int r = 0; r < 4; ++r) {
        int row = w * 32 + mi * 16 + lr + r;
        int col = ci * 16 + lm;
        Cg[(size_t)row * LDQ + col] = (bf16)(oacc[mi][ci][r] * inv[mi][r]);
      }
}

// ---------------------------------------------------------------------------
extern "C" void kernel_launch(void* const* d_in, const int* in_sizes, int n_in,
                              void* d_out, int out_size, void* d_ws, size_t ws_size,
                              hipStream_t stream) {
  const float* x = (const float*)d_in[0];
  const float* Wq = (const float*)d_in[1];
  const float* Wk = (const float*)d_in[2];
  const float* Wv = (const float*)d_in[3];
  const float* Wo = (const float*)d_in[4];
  const float* bo = (const float*)d_in[5];
  float* out = (float*)d_out;

  constexpr int M = 512 * 128;      // 65536 tokens
  constexpr int D = 768;
  constexpr size_t XB_BYTES = (size_t)M * D * 2;            // 100663296
  constexpr size_t WQKV_BYTES = (size_t)3 * D * D * 2;      // 3538944
  constexpr size_t WOT_BYTES = (size_t)D * D * 2;           // 1179648

  char* ws = (char*)d_ws;
  bf16* xb = (bf16*)ws;
  bf16* wqkv = (bf16*)(ws + XB_BYTES);
  bf16* wot = (bf16*)(ws + XB_BYTES + WQKV_BYTES);
  bf16* qkv = (bf16*)(ws + XB_BYTES + WQKV_BYTES + WOT_BYTES);  // [M][2304]

  // 1) cast x
  cast_x_bf16<<<(M * D) / 1024, 256, 0, stream>>>(x, xb, M * D);
  // 2) weight transposes
  dim3 tb(32, 8);
  transpose_cast_w<<<dim3(24, 24), tb, 0, stream>>>(Wq, wqkv);
  transpose_cast_w<<<dim3(24, 24), tb, 0, stream>>>(Wk, wqkv + 768 * 768);
  transpose_cast_w<<<dim3(24, 24), tb, 0, stream>>>(Wv, wqkv + 2 * 768 * 768);
  transpose_cast_w<<<dim3(24, 24), tb, 0, stream>>>(Wo, wot);
  // 3) fused QKV GEMM: [65536 x 768] * [768 x 2304] -> bf16 [65536 x 2304]
  gemm128<false><<<dim3(M / 128, 2304 / 128), 256, 0, stream>>>(
      xb, 768, wqkv, 768, qkv, 2304, nullptr, 768);
  // 4) attention; ctx written in-place over Q region of qkv
  attn_kernel<<<512 * 12, 256, 0, stream>>>(qkv, qkv);
  // 5) output GEMM: ctx [65536 x 768] (lda=2304) * Wo -> fp32 out + bias
  gemm128<true><<<dim3(M / 128, 768 / 128), 256, 0, stream>>>(
      qkv, 2304, wot, 768, out, 768, bo, 768);
}